// Round 8
// baseline (534.868 us; speedup 1.0000x reference)
//
#include <hip/hip_runtime.h>

#define Hm 2048
#define Em 64
#define Tm 32768
#define KSEL 640        // int(1.25 * 32768 / 64)
#define CHK 16          // k per staged chunk
#define BT  512         // tokens per block in partial GEMM

typedef unsigned int u32;

__device__ __forceinline__ float4 ld4(const float* p) {
    return *reinterpret_cast<const float4*>(p);
}

// ---------------------------------------------------------------------------
// K0: W [64][2048] -> Wt [2048][64] (k-major, one-time)
// ---------------------------------------------------------------------------
__global__ __launch_bounds__(256) void k_wt(
    const float* __restrict__ W, float* __restrict__ Wt)
{
    __shared__ float T[64][65];
    const int tid = threadIdx.x;
    const int kb = blockIdx.x * 64;
    const int lc = tid & 63;
    const int lr = tid >> 6;
#pragma unroll
    for (int r = 0; r < 16; ++r) {
        const int e = r * 4 + lr;
        T[e][lc] = W[(size_t)e * Hm + kb + lc];
    }
    __syncthreads();
#pragma unroll
    for (int r = 0; r < 16; ++r) {
        const int kk = r * 4 + lr;
        Wt[(size_t)(kb + kk) * Em + lc] = T[lc][kk];
    }
}

// ---------------------------------------------------------------------------
// K1: split-K partial GEMM. grid = 64*nkq blocks x 256 threads (4 waves).
// Wave = 128 tok x 64 exp; thread tile = 16 tok x 8 exp.
// Token->lane map interleaved by 4 (tok = wb + g*32 + lr*4 + m) so each
// A-read's 8 lane-addresses (16B each) tile all 32 banks -> conflict-free.
// A staged k-major with b128 writes (thread loads 4 tok x 8 k, transposes in
// regs). acc[16][8] = 128 VGPR -> launch_bounds(256,2) (R5 spill lesson).
// ---------------------------------------------------------------------------
__global__ __launch_bounds__(256, 2) void k_router_partial(
    const float* __restrict__ hid, const float* __restrict__ Wt,
    float* __restrict__ pl, int nkq)
{
    __shared__ __align__(16) float As[CHK][BT + 4];   // 33 KB (stride 516)
    __shared__ __align__(16) float Bs[CHK][68];       // 4.3 KB

    const int t  = threadIdx.x;
    const int tb = blockIdx.x & 63;
    const int kq = blockIdx.x >> 6;
    const int t0 = tb * BT;
    const int k0 = kq * (Hm / nkq);
    const int nchunks = (Hm / nkq) / CHK;

    // staging map: thread loads 4 tokens (tq*4..+3) x 8 k (kh*8..+7)
    const int tq = t & 127;
    const int kh = t >> 7;
    const float* a0p = hid + (size_t)(t0 + tq * 4 + 0) * Hm + k0 + kh * 8;
    const float* a1p = hid + (size_t)(t0 + tq * 4 + 1) * Hm + k0 + kh * 8;
    const float* a2p = hid + (size_t)(t0 + tq * 4 + 2) * Hm + k0 + kh * 8;
    const float* a3p = hid + (size_t)(t0 + tq * 4 + 3) * Hm + k0 + kh * 8;
    const float* bpp = Wt + (size_t)k0 * Em + t * 4;

    float acc[16][8];
#pragma unroll
    for (int i = 0; i < 16; ++i)
#pragma unroll
        for (int j = 0; j < 8; ++j) acc[i][j] = 0.f;

    float4 ar[4][2];   // [token][half]: 8 k-values per token
    float4 br;

    auto loadAB = [&](int c) {
        const int o = c * CHK;
        ar[0][0] = ld4(a0p + o); ar[0][1] = ld4(a0p + o + 4);
        ar[1][0] = ld4(a1p + o); ar[1][1] = ld4(a1p + o + 4);
        ar[2][0] = ld4(a2p + o); ar[2][1] = ld4(a2p + o + 4);
        ar[3][0] = ld4(a3p + o); ar[3][1] = ld4(a3p + o + 4);
        br = ld4(bpp + (size_t)o * Em);
    };
    auto writeAB = [&]() {
        // A: for each of 8 kk, gather the 4 tokens' value -> one b128
#pragma unroll
        for (int h = 0; h < 2; ++h) {
            const float* f0 = (const float*)&ar[0][h];
            const float* f1 = (const float*)&ar[1][h];
            const float* f2 = (const float*)&ar[2][h];
            const float* f3 = (const float*)&ar[3][h];
#pragma unroll
            for (int j = 0; j < 4; ++j) {
                const int kk = kh * 8 + h * 4 + j;
                *reinterpret_cast<float4*>(&As[kk][tq * 4]) =
                    make_float4(f0[j], f1[j], f2[j], f3[j]);
            }
        }
        const int F = t * 4;
        *reinterpret_cast<float4*>(&Bs[F >> 6][F & 63]) = br;
    };

    const int l  = t & 63;
    const int w  = t >> 6;
    const int lr = l >> 3;
    const int lc = l & 7;
    const int wb = w * 128;       // wave token base

    loadAB(0);

    for (int c = 0; c < nchunks; ++c) {
        writeAB();
        __syncthreads();
        if (c + 1 < nchunks) loadAB(c + 1);

#pragma unroll
        for (int kk = 0; kk < CHK; ++kk) {
            const float4 b0 = ld4(&Bs[kk][lc * 8]);
            const float4 b1 = ld4(&Bs[kk][lc * 8 + 4]);
            const float bv[8] = { b0.x, b0.y, b0.z, b0.w,
                                  b1.x, b1.y, b1.z, b1.w };
#pragma unroll
            for (int g = 0; g < 4; ++g) {
                const float4 a = ld4(&As[kk][wb + g * 32 + lr * 4]);
                const float av[4] = { a.x, a.y, a.z, a.w };
#pragma unroll
                for (int m = 0; m < 4; ++m)
#pragma unroll
                    for (int j = 0; j < 8; ++j)
                        acc[g * 4 + m][j] =
                            fmaf(av[m], bv[j], acc[g * 4 + m][j]);
            }
        }
        __syncthreads();
    }

    // epilogue: write partials
#pragma unroll
    for (int g = 0; g < 4; ++g)
#pragma unroll
        for (int m = 0; m < 4; ++m) {
            const int tok = t0 + wb + g * 32 + lr * 4 + m;
            float* dst = pl + ((size_t)kq * Tm + tok) * Em + lc * 8;
            const float* a = acc[g * 4 + m];
            *reinterpret_cast<float4*>(dst) =
                make_float4(a[0], a[1], a[2], a[3]);
            *reinterpret_cast<float4*>(dst + 4) =
                make_float4(a[4], a[5], a[6], a[7]);
        }
}

// ---------------------------------------------------------------------------
// K1b: reduce split-K partials + softmax. One thread per token.
// ---------------------------------------------------------------------------
__global__ __launch_bounds__(128) void k_reduce(
    const float* __restrict__ pl, int nkq,
    float* __restrict__ probs, float* __restrict__ probsT)
{
    const int t = blockIdx.x * 128 + threadIdx.x;
    float lg[64];
    {
        const float* src = pl + (size_t)t * Em;
#pragma unroll
        for (int j = 0; j < 16; ++j) {
            const float4 x = ld4(src + 4 * j);
            lg[4 * j + 0] = x.x; lg[4 * j + 1] = x.y;
            lg[4 * j + 2] = x.z; lg[4 * j + 3] = x.w;
        }
    }
    for (int q = 1; q < nkq; ++q) {
        const float* src = pl + ((size_t)q * Tm + t) * Em;
#pragma unroll
        for (int j = 0; j < 16; ++j) {
            const float4 x = ld4(src + 4 * j);
            lg[4 * j + 0] += x.x; lg[4 * j + 1] += x.y;
            lg[4 * j + 2] += x.z; lg[4 * j + 3] += x.w;
        }
    }
    float mx = lg[0];
#pragma unroll
    for (int e = 1; e < 64; ++e) mx = fmaxf(mx, lg[e]);
    float s = 0.f;
#pragma unroll
    for (int e = 0; e < 64; ++e) { lg[e] = __expf(lg[e] - mx); s += lg[e]; }
    const float inv = 1.0f / s;
#pragma unroll
    for (int e = 0; e < 64; ++e) lg[e] *= inv;

    float* po = probs + (size_t)t * Em;
#pragma unroll
    for (int j = 0; j < 16; ++j)
        *reinterpret_cast<float4*>(po + 4 * j) =
            make_float4(lg[4 * j], lg[4 * j + 1], lg[4 * j + 2], lg[4 * j + 3]);
#pragma unroll
    for (int e = 0; e < 64; ++e)
        probsT[(size_t)e * Tm + t] = lg[e];
}

// ---------------------------------------------------------------------------
// K2: per-expert top-640 radix select, passes 11/11/10 bits.
// No key staging (rows are L2/L3-resident; re-read per pass). LDS spent on
// 16 wave-private 2048-bin histograms -> pass-1 atomic contention / 16.
// ---------------------------------------------------------------------------
__device__ __forceinline__ void suffix_scan_fast(u32* h, u32* wsum, int nbins) {
    const int tid  = threadIdx.x;
    const int lane = tid & 63;
    const int w    = tid >> 6;
    u32 a0, a1, s;
    if (nbins == 2048) {
        a0 = h[2 * tid]; a1 = h[2 * tid + 1]; s = a0 + a1;
    } else {
        a0 = h[tid]; a1 = 0; s = a0;
    }
    u32 v = s;
#pragma unroll
    for (int off = 1; off < 64; off <<= 1) {
        const u32 tv = __shfl_down(v, off, 64);
        if (lane + off < 64) v += tv;
    }
    if (lane == 0) wsum[w] = v;
    __syncthreads();
    u32 woff = 0;
#pragma unroll
    for (int j = 0; j < 16; ++j) woff += (j > w) ? wsum[j] : 0u;
    const u32 after = v - s + woff;
    if (nbins == 2048) {
        h[2 * tid]     = after + s;
        h[2 * tid + 1] = after + a1;
    } else {
        h[tid] = after + s;
    }
    __syncthreads();
}

__global__ __launch_bounds__(1024) void k_select(
    const float* __restrict__ probsT, float* __restrict__ dT)
{
    __shared__ u32 hist[16][2048];   // 128 KB: wave-private p1; rows 1,2 reused
    __shared__ u32 tielist[2048];    // 8 KB
    __shared__ u32 wsum[16];
    __shared__ u32 sh_need[4];
    __shared__ u32 sh_bins[3];
    __shared__ u32 sh_ntie, sh_take, sh_nlist;

    const int tid = threadIdx.x;
    const int wv  = tid >> 6;
    const int e   = blockIdx.x;
    const float*  row  = probsT + (size_t)e * Tm;
    const float4* row4 = reinterpret_cast<const float4*>(row);

    // zero all 16 histograms (32768 words)
    {
        u32* hf = &hist[0][0];
        const uint4 z = make_uint4(0, 0, 0, 0);
#pragma unroll
        for (int k = 0; k < 8; ++k)
            *reinterpret_cast<uint4*>(&hf[4 * (tid + k * 1024)]) = z;
    }
    if (tid == 0) sh_need[0] = KSEL;
    __syncthreads();

    // ---- pass 1: bits [31:21], wave-private histograms ----
    {
        u32* myh = hist[wv];
        for (int i = tid; i < Tm / 4; i += 1024) {
            const float4 x = row4[i];
            atomicAdd(&myh[__float_as_uint(x.x) >> 21], 1u);
            atomicAdd(&myh[__float_as_uint(x.y) >> 21], 1u);
            atomicAdd(&myh[__float_as_uint(x.z) >> 21], 1u);
            atomicAdd(&myh[__float_as_uint(x.w) >> 21], 1u);
        }
    }
    __syncthreads();
    // merge 16 -> totals (thread owns bins tid, tid+1024)
    {
        u32 t0 = 0, t1 = 0;
#pragma unroll
        for (int w2 = 0; w2 < 16; ++w2) {
            t0 += hist[w2][tid];
            t1 += hist[w2][tid + 1024];
        }
        __syncthreads();
        hist[0][tid] = t0; hist[0][tid + 1024] = t1;
        __syncthreads();
    }
    suffix_scan_fast(hist[0], wsum, 2048);
    {
        const u32 need = sh_need[0];
#pragma unroll
        for (int r = 0; r < 2; ++r) {
            const int b = tid + r * 1024;
            const u32 sb = hist[0][b];
            const u32 sa = (b + 1 < 2048) ? hist[0][b + 1] : 0u;
            if (sb >= need && sa < need) { sh_bins[0] = (u32)b; sh_need[1] = need - sa; }
        }
    }
    __syncthreads();
    const u32 b1 = sh_bins[0];

    // ---- pass 2: bits [20:10] (filtered -> low volume, single hist) ----
    hist[1][tid] = 0; hist[1][tid + 1024] = 0;
    __syncthreads();
    for (int i = tid; i < Tm; i += 1024) {
        const u32 k = __float_as_uint(row[i]);
        if ((k >> 21) == b1) atomicAdd(&hist[1][(k >> 10) & 0x7FFu], 1u);
    }
    __syncthreads();
    suffix_scan_fast(hist[1], wsum, 2048);
    {
        const u32 need = sh_need[1];
#pragma unroll
        for (int r = 0; r < 2; ++r) {
            const int b = tid + r * 1024;
            const u32 sb = hist[1][b];
            const u32 sa = (b + 1 < 2048) ? hist[1][b + 1] : 0u;
            if (sb >= need && sa < need) { sh_bins[1] = (u32)b; sh_need[2] = need - sa; }
        }
    }
    __syncthreads();
    const u32 p2 = (b1 << 11) | sh_bins[1];

    // ---- pass 3: bits [9:0], 1024 bins ----
    hist[2][tid & 1023] = 0;
    __syncthreads();
    for (int i = tid; i < Tm; i += 1024) {
        const u32 k = __float_as_uint(row[i]);
        if ((k >> 10) == p2) atomicAdd(&hist[2][k & 0x3FFu], 1u);
    }
    __syncthreads();
    suffix_scan_fast(hist[2], wsum, 1024);
    if (tid < 1024) {
        const u32 need = sh_need[2];
        const u32 sb = hist[2][tid];
        const u32 sa = (tid + 1 < 1024) ? hist[2][tid + 1] : 0u;
        if (sb >= need && sa < need) {
            sh_bins[2] = (u32)tid;
            sh_take = need - sa;
            sh_ntie = sb - sa;
        }
    }
    __syncthreads();
    const u32 Kstar = (p2 << 10) | sh_bins[2];
    const u32 take = sh_take, ntie = sh_ntie;

    // ---- scatter: full coalesced row of dT ----
    float4* drow4 = reinterpret_cast<float4*>(dT + (size_t)e * Tm);
    if (ntie == take) {
        for (int i = tid; i < Tm / 4; i += 1024) {
            const float4 x = row4[i];
            float4 o;
            o.x = (__float_as_uint(x.x) >= Kstar) ? x.x : 0.f;
            o.y = (__float_as_uint(x.y) >= Kstar) ? x.y : 0.f;
            o.z = (__float_as_uint(x.z) >= Kstar) ? x.z : 0.f;
            o.w = (__float_as_uint(x.w) >= Kstar) ? x.w : 0.f;
            drow4[i] = o;
        }
    } else {
        float* drow = dT + (size_t)e * Tm;
        if (tid == 0) sh_nlist = 0;
        __syncthreads();
        for (int i = tid; i < Tm; i += 1024) {
            const float v = row[i];
            const u32 k = __float_as_uint(v);
            drow[i] = (k > Kstar) ? v : 0.f;
            if (k == Kstar) {
                const u32 idx = atomicAdd(&sh_nlist, 1u);
                if (idx < 2048u) tielist[idx] = (u32)i;
            }
        }
        __syncthreads();
        const int n = (int)(sh_nlist < 2048u ? sh_nlist : 2048u);
        for (int i = tid; i < n; i += 1024) {
            const u32 tt = tielist[i];
            int r = 0;
            for (int j = 0; j < n; ++j) r += (tielist[j] < tt);
            if (r < (int)take) drow[tt] = __uint_as_float(Kstar);
        }
    }
}

// ---------------------------------------------------------------------------
// K3: transpose dT [E][T] -> dispatch [T][E] + combine, fused.
// ---------------------------------------------------------------------------
__global__ __launch_bounds__(256) void k_finish(
    const float* __restrict__ dT, float* __restrict__ dispatch,
    float* __restrict__ combine)
{
    __shared__ float Ls[64][65];
    const int tid = threadIdx.x;
    const int t0 = blockIdx.x * 64;
    {
        const int e = tid >> 2, tq = tid & 3;
        const float* src = dT + (size_t)e * Tm + t0 + tq * 16;
#pragma unroll
        for (int u = 0; u < 4; ++u) {
            const float4 x = ld4(src + 4 * u);
            Ls[tq * 16 + 4 * u + 0][e] = x.x;
            Ls[tq * 16 + 4 * u + 1][e] = x.y;
            Ls[tq * 16 + 4 * u + 2][e] = x.z;
            Ls[tq * 16 + 4 * u + 3][e] = x.w;
        }
    }
    __syncthreads();
    const int t = tid >> 2, q = tid & 3;
    float v[16];
    float s = 0.f;
#pragma unroll
    for (int u = 0; u < 16; ++u) { v[u] = Ls[t][q * 16 + u]; s += v[u]; }
    s += __shfl_xor(s, 1, 4);
    s += __shfl_xor(s, 2, 4);
    const float inv = (s > 0.f) ? 1.0f / s : 0.f;
    float* dp = dispatch + (size_t)(t0 + t) * Em + q * 16;
    float* cb = combine  + (size_t)(t0 + t) * Em + q * 16;
#pragma unroll
    for (int u = 0; u < 4; ++u) {
        *reinterpret_cast<float4*>(dp + 4 * u) =
            make_float4(v[4 * u], v[4 * u + 1], v[4 * u + 2], v[4 * u + 3]);
        *reinterpret_cast<float4*>(cb + 4 * u) =
            make_float4(v[4 * u] * inv, v[4 * u + 1] * inv,
                        v[4 * u + 2] * inv, v[4 * u + 3] * inv);
    }
}

// ---------------------------------------------------------------------------
extern "C" void kernel_launch(void* const* d_in, const int* in_sizes, int n_in,
                              void* d_out, int out_size, void* d_ws, size_t ws_size,
                              hipStream_t stream) {
    const float* hid = (const float*)d_in[0];
    const float* W   = (const float*)d_in[1];
    float* out      = (float*)d_out;
    float* dispatch = out;
    float* combine  = out + (size_t)Tm * Em;
    float* probs    = out + 2 * (size_t)Tm * Em;

    const size_t wtB = sizeof(float) * (size_t)Hm * Em;   // 512 KB
    const size_t teB = sizeof(float) * (size_t)Tm * Em;   // 8 MB
    char* ws = (char*)d_ws;

    float* Wt = (float*)ws;
    size_t off = wtB;

    // pick largest split-K that fits: partials (nkq*teB) + probsT + dT
    int nkq = 1;
    if      (ws_size >= off + (8 + 2) * teB) nkq = 8;
    else if (ws_size >= off + (4 + 2) * teB) nkq = 4;
    else if (ws_size >= off + (2 + 2) * teB) nkq = 2;

    float* pl = (float*)(ws + off);
    off += (size_t)nkq * teB;
    float* probsT = (float*)(ws + off); off += teB;
    float* dT     = (float*)(ws + off); off += teB;

    k_wt<<<Hm / 64, 256, 0, stream>>>(W, Wt);
    k_router_partial<<<(Tm / BT) * nkq, 256, 0, stream>>>(hid, Wt, pl, nkq);
    k_reduce<<<Tm / 128, 128, 0, stream>>>(pl, nkq, probs, probsT);
    k_select<<<Em, 1024, 0, stream>>>(probsT, dT);
    k_finish<<<Tm / 64, 256, 0, stream>>>(dT, dispatch, combine);
}

// Round 9
// 227.051 us; speedup vs baseline: 2.3557x; 2.3557x over previous
//
#include <hip/hip_runtime.h>

#define Hm 2048
#define Em 64
#define Tm 32768
#define KSEL 640        // int(1.25 * 32768 / 64)
#define CHK 16          // k per staged chunk
#define BT  512         // tokens per block in partial GEMM

typedef unsigned int u32;

__device__ __forceinline__ float4 ld4(const float* p) {
    return *reinterpret_cast<const float4*>(p);
}

// ---------------------------------------------------------------------------
// K0: W [64][2048] -> Wt [2048][64] (k-major, one-time)
// ---------------------------------------------------------------------------
__global__ __launch_bounds__(256) void k_wt(
    const float* __restrict__ W, float* __restrict__ Wt)
{
    __shared__ float T[64][65];
    const int tid = threadIdx.x;
    const int kb = blockIdx.x * 64;
    const int lc = tid & 63;
    const int lr = tid >> 6;
#pragma unroll
    for (int r = 0; r < 16; ++r) {
        const int e = r * 4 + lr;
        T[e][lc] = W[(size_t)e * Hm + kb + lc];
    }
    __syncthreads();
#pragma unroll
    for (int r = 0; r < 16; ++r) {
        const int kk = r * 4 + lr;
        Wt[(size_t)(kb + kk) * Em + lc] = T[lc][kk];
    }
}

// ---------------------------------------------------------------------------
// K1: split-K partial GEMM. grid = 64*nkq blocks x 256 threads (4 waves).
// Wave = 128 tok x 64 exp; thread tile = 16 tok x 8 exp.
// launch_bounds(256, 1): empirical allocator law on this toolchain is
// cap = 256 / min_waves_arg. acc[16][8]=128 regs + staging ~200 total:
// w=2 capped at 128 -> scratch spill (R8: 505us, 2.6GB HBM). w=1 -> 256 cap.
// ---------------------------------------------------------------------------
__global__ __launch_bounds__(256, 1) void k_router_partial(
    const float* __restrict__ hid, const float* __restrict__ Wt,
    float* __restrict__ pl, int nkq)
{
    __shared__ __align__(16) float As[CHK][BT + 4];   // 33 KB (stride 516)
    __shared__ __align__(16) float Bs[CHK][68];       // 4.3 KB

    const int t  = threadIdx.x;
    const int tb = blockIdx.x & 63;
    const int kq = blockIdx.x >> 6;
    const int t0 = tb * BT;
    const int k0 = kq * (Hm / nkq);
    const int nchunks = (Hm / nkq) / CHK;

    // staging map: thread loads 4 tokens (tq*4..+3) x 8 k (kh*8..+7)
    const int tq = t & 127;
    const int kh = t >> 7;
    const float* a0p = hid + (size_t)(t0 + tq * 4 + 0) * Hm + k0 + kh * 8;
    const float* a1p = hid + (size_t)(t0 + tq * 4 + 1) * Hm + k0 + kh * 8;
    const float* a2p = hid + (size_t)(t0 + tq * 4 + 2) * Hm + k0 + kh * 8;
    const float* a3p = hid + (size_t)(t0 + tq * 4 + 3) * Hm + k0 + kh * 8;
    const float* bpp = Wt + (size_t)k0 * Em + t * 4;

    float acc[16][8];
#pragma unroll
    for (int i = 0; i < 16; ++i)
#pragma unroll
        for (int j = 0; j < 8; ++j) acc[i][j] = 0.f;

    float4 ar[4][2];   // [token][half]: 8 k-values per token
    float4 br;

    auto loadAB = [&](int c) {
        const int o = c * CHK;
        ar[0][0] = ld4(a0p + o); ar[0][1] = ld4(a0p + o + 4);
        ar[1][0] = ld4(a1p + o); ar[1][1] = ld4(a1p + o + 4);
        ar[2][0] = ld4(a2p + o); ar[2][1] = ld4(a2p + o + 4);
        ar[3][0] = ld4(a3p + o); ar[3][1] = ld4(a3p + o + 4);
        br = ld4(bpp + (size_t)o * Em);
    };
    auto writeAB = [&]() {
        // A: for each of 8 kk, gather the 4 tokens' value -> one b128
#pragma unroll
        for (int h = 0; h < 2; ++h) {
            const float* f0 = (const float*)&ar[0][h];
            const float* f1 = (const float*)&ar[1][h];
            const float* f2 = (const float*)&ar[2][h];
            const float* f3 = (const float*)&ar[3][h];
#pragma unroll
            for (int j = 0; j < 4; ++j) {
                const int kk = kh * 8 + h * 4 + j;
                *reinterpret_cast<float4*>(&As[kk][tq * 4]) =
                    make_float4(f0[j], f1[j], f2[j], f3[j]);
            }
        }
        const int F = t * 4;
        *reinterpret_cast<float4*>(&Bs[F >> 6][F & 63]) = br;
    };

    const int l  = t & 63;
    const int w  = t >> 6;
    const int lr = l >> 3;
    const int lc = l & 7;
    const int wb = w * 128;       // wave token base

    loadAB(0);

    for (int c = 0; c < nchunks; ++c) {
        writeAB();
        __syncthreads();
        if (c + 1 < nchunks) loadAB(c + 1);

#pragma unroll
        for (int kk = 0; kk < CHK; ++kk) {
            const float4 b0 = ld4(&Bs[kk][lc * 8]);
            const float4 b1 = ld4(&Bs[kk][lc * 8 + 4]);
            const float bv[8] = { b0.x, b0.y, b0.z, b0.w,
                                  b1.x, b1.y, b1.z, b1.w };
#pragma unroll
            for (int g = 0; g < 4; ++g) {
                const float4 a = ld4(&As[kk][wb + g * 32 + lr * 4]);
                const float av[4] = { a.x, a.y, a.z, a.w };
#pragma unroll
                for (int m = 0; m < 4; ++m)
#pragma unroll
                    for (int j = 0; j < 8; ++j)
                        acc[g * 4 + m][j] =
                            fmaf(av[m], bv[j], acc[g * 4 + m][j]);
            }
        }
        __syncthreads();
    }

    // epilogue: write partials
#pragma unroll
    for (int g = 0; g < 4; ++g)
#pragma unroll
        for (int m = 0; m < 4; ++m) {
            const int tok = t0 + wb + g * 32 + lr * 4 + m;
            float* dst = pl + ((size_t)kq * Tm + tok) * Em + lc * 8;
            const float* a = acc[g * 4 + m];
            *reinterpret_cast<float4*>(dst) =
                make_float4(a[0], a[1], a[2], a[3]);
            *reinterpret_cast<float4*>(dst + 4) =
                make_float4(a[4], a[5], a[6], a[7]);
        }
}

// ---------------------------------------------------------------------------
// K1b: reduce split-K partials + softmax. One thread per token.
// ---------------------------------------------------------------------------
__global__ __launch_bounds__(128) void k_reduce(
    const float* __restrict__ pl, int nkq,
    float* __restrict__ probs, float* __restrict__ probsT)
{
    const int t = blockIdx.x * 128 + threadIdx.x;
    float lg[64];
    {
        const float* src = pl + (size_t)t * Em;
#pragma unroll
        for (int j = 0; j < 16; ++j) {
            const float4 x = ld4(src + 4 * j);
            lg[4 * j + 0] = x.x; lg[4 * j + 1] = x.y;
            lg[4 * j + 2] = x.z; lg[4 * j + 3] = x.w;
        }
    }
    for (int q = 1; q < nkq; ++q) {
        const float* src = pl + ((size_t)q * Tm + t) * Em;
#pragma unroll
        for (int j = 0; j < 16; ++j) {
            const float4 x = ld4(src + 4 * j);
            lg[4 * j + 0] += x.x; lg[4 * j + 1] += x.y;
            lg[4 * j + 2] += x.z; lg[4 * j + 3] += x.w;
        }
    }
    float mx = lg[0];
#pragma unroll
    for (int e = 1; e < 64; ++e) mx = fmaxf(mx, lg[e]);
    float s = 0.f;
#pragma unroll
    for (int e = 0; e < 64; ++e) { lg[e] = __expf(lg[e] - mx); s += lg[e]; }
    const float inv = 1.0f / s;
#pragma unroll
    for (int e = 0; e < 64; ++e) lg[e] *= inv;

    float* po = probs + (size_t)t * Em;
#pragma unroll
    for (int j = 0; j < 16; ++j)
        *reinterpret_cast<float4*>(po + 4 * j) =
            make_float4(lg[4 * j], lg[4 * j + 1], lg[4 * j + 2], lg[4 * j + 3]);
#pragma unroll
    for (int e = 0; e < 64; ++e)
        probsT[(size_t)e * Tm + t] = lg[e];
}

// ---------------------------------------------------------------------------
// K2: per-expert top-640 radix select, passes 11/11/10 bits.
// No key staging (rows are L2/L3-resident; re-read per pass). LDS spent on
// 16 wave-private 2048-bin histograms -> pass-1 atomic contention / 16.
// ---------------------------------------------------------------------------
__device__ __forceinline__ void suffix_scan_fast(u32* h, u32* wsum, int nbins) {
    const int tid  = threadIdx.x;
    const int lane = tid & 63;
    const int w    = tid >> 6;
    u32 a0, a1, s;
    if (nbins == 2048) {
        a0 = h[2 * tid]; a1 = h[2 * tid + 1]; s = a0 + a1;
    } else {
        a0 = h[tid]; a1 = 0; s = a0;
    }
    u32 v = s;
#pragma unroll
    for (int off = 1; off < 64; off <<= 1) {
        const u32 tv = __shfl_down(v, off, 64);
        if (lane + off < 64) v += tv;
    }
    if (lane == 0) wsum[w] = v;
    __syncthreads();
    u32 woff = 0;
#pragma unroll
    for (int j = 0; j < 16; ++j) woff += (j > w) ? wsum[j] : 0u;
    const u32 after = v - s + woff;
    if (nbins == 2048) {
        h[2 * tid]     = after + s;
        h[2 * tid + 1] = after + a1;
    } else {
        h[tid] = after + s;
    }
    __syncthreads();
}

__global__ __launch_bounds__(1024) void k_select(
    const float* __restrict__ probsT, float* __restrict__ dT)
{
    __shared__ u32 hist[16][2048];   // 128 KB: wave-private p1; rows 1,2 reused
    __shared__ u32 tielist[2048];    // 8 KB
    __shared__ u32 wsum[16];
    __shared__ u32 sh_need[4];
    __shared__ u32 sh_bins[3];
    __shared__ u32 sh_ntie, sh_take, sh_nlist;

    const int tid = threadIdx.x;
    const int wv  = tid >> 6;
    const int e   = blockIdx.x;
    const float*  row  = probsT + (size_t)e * Tm;
    const float4* row4 = reinterpret_cast<const float4*>(row);

    // zero all 16 histograms (32768 words)
    {
        u32* hf = &hist[0][0];
        const uint4 z = make_uint4(0, 0, 0, 0);
#pragma unroll
        for (int k = 0; k < 8; ++k)
            *reinterpret_cast<uint4*>(&hf[4 * (tid + k * 1024)]) = z;
    }
    if (tid == 0) sh_need[0] = KSEL;
    __syncthreads();

    // ---- pass 1: bits [31:21], wave-private histograms ----
    {
        u32* myh = hist[wv];
        for (int i = tid; i < Tm / 4; i += 1024) {
            const float4 x = row4[i];
            atomicAdd(&myh[__float_as_uint(x.x) >> 21], 1u);
            atomicAdd(&myh[__float_as_uint(x.y) >> 21], 1u);
            atomicAdd(&myh[__float_as_uint(x.z) >> 21], 1u);
            atomicAdd(&myh[__float_as_uint(x.w) >> 21], 1u);
        }
    }
    __syncthreads();
    // merge 16 -> totals (thread owns bins tid, tid+1024)
    {
        u32 t0 = 0, t1 = 0;
#pragma unroll
        for (int w2 = 0; w2 < 16; ++w2) {
            t0 += hist[w2][tid];
            t1 += hist[w2][tid + 1024];
        }
        __syncthreads();
        hist[0][tid] = t0; hist[0][tid + 1024] = t1;
        __syncthreads();
    }
    suffix_scan_fast(hist[0], wsum, 2048);
    {
        const u32 need = sh_need[0];
#pragma unroll
        for (int r = 0; r < 2; ++r) {
            const int b = tid + r * 1024;
            const u32 sb = hist[0][b];
            const u32 sa = (b + 1 < 2048) ? hist[0][b + 1] : 0u;
            if (sb >= need && sa < need) { sh_bins[0] = (u32)b; sh_need[1] = need - sa; }
        }
    }
    __syncthreads();
    const u32 b1 = sh_bins[0];

    // ---- pass 2: bits [20:10] (filtered -> low volume, single hist) ----
    hist[1][tid] = 0; hist[1][tid + 1024] = 0;
    __syncthreads();
    for (int i = tid; i < Tm; i += 1024) {
        const u32 k = __float_as_uint(row[i]);
        if ((k >> 21) == b1) atomicAdd(&hist[1][(k >> 10) & 0x7FFu], 1u);
    }
    __syncthreads();
    suffix_scan_fast(hist[1], wsum, 2048);
    {
        const u32 need = sh_need[1];
#pragma unroll
        for (int r = 0; r < 2; ++r) {
            const int b = tid + r * 1024;
            const u32 sb = hist[1][b];
            const u32 sa = (b + 1 < 2048) ? hist[1][b + 1] : 0u;
            if (sb >= need && sa < need) { sh_bins[1] = (u32)b; sh_need[2] = need - sa; }
        }
    }
    __syncthreads();
    const u32 p2 = (b1 << 11) | sh_bins[1];

    // ---- pass 3: bits [9:0], 1024 bins ----
    hist[2][tid & 1023] = 0;
    __syncthreads();
    for (int i = tid; i < Tm; i += 1024) {
        const u32 k = __float_as_uint(row[i]);
        if ((k >> 10) == p2) atomicAdd(&hist[2][k & 0x3FFu], 1u);
    }
    __syncthreads();
    suffix_scan_fast(hist[2], wsum, 1024);
    if (tid < 1024) {
        const u32 need = sh_need[2];
        const u32 sb = hist[2][tid];
        const u32 sa = (tid + 1 < 1024) ? hist[2][tid + 1] : 0u;
        if (sb >= need && sa < need) {
            sh_bins[2] = (u32)tid;
            sh_take = need - sa;
            sh_ntie = sb - sa;
        }
    }
    __syncthreads();
    const u32 Kstar = (p2 << 10) | sh_bins[2];
    const u32 take = sh_take, ntie = sh_ntie;

    // ---- scatter: full coalesced row of dT ----
    float4* drow4 = reinterpret_cast<float4*>(dT + (size_t)e * Tm);
    if (ntie == take) {
        for (int i = tid; i < Tm / 4; i += 1024) {
            const float4 x = row4[i];
            float4 o;
            o.x = (__float_as_uint(x.x) >= Kstar) ? x.x : 0.f;
            o.y = (__float_as_uint(x.y) >= Kstar) ? x.y : 0.f;
            o.z = (__float_as_uint(x.z) >= Kstar) ? x.z : 0.f;
            o.w = (__float_as_uint(x.w) >= Kstar) ? x.w : 0.f;
            drow4[i] = o;
        }
    } else {
        float* drow = dT + (size_t)e * Tm;
        if (tid == 0) sh_nlist = 0;
        __syncthreads();
        for (int i = tid; i < Tm; i += 1024) {
            const float v = row[i];
            const u32 k = __float_as_uint(v);
            drow[i] = (k > Kstar) ? v : 0.f;
            if (k == Kstar) {
                const u32 idx = atomicAdd(&sh_nlist, 1u);
                if (idx < 2048u) tielist[idx] = (u32)i;
            }
        }
        __syncthreads();
        const int n = (int)(sh_nlist < 2048u ? sh_nlist : 2048u);
        for (int i = tid; i < n; i += 1024) {
            const u32 tt = tielist[i];
            int r = 0;
            for (int j = 0; j < n; ++j) r += (tielist[j] < tt);
            if (r < (int)take) drow[tt] = __uint_as_float(Kstar);
        }
    }
}

// ---------------------------------------------------------------------------
// K3: transpose dT [E][T] -> dispatch [T][E] + combine, fused.
// ---------------------------------------------------------------------------
__global__ __launch_bounds__(256) void k_finish(
    const float* __restrict__ dT, float* __restrict__ dispatch,
    float* __restrict__ combine)
{
    __shared__ float Ls[64][65];
    const int tid = threadIdx.x;
    const int t0 = blockIdx.x * 64;
    {
        const int e = tid >> 2, tq = tid & 3;
        const float* src = dT + (size_t)e * Tm + t0 + tq * 16;
#pragma unroll
        for (int u = 0; u < 4; ++u) {
            const float4 x = ld4(src + 4 * u);
            Ls[tq * 16 + 4 * u + 0][e] = x.x;
            Ls[tq * 16 + 4 * u + 1][e] = x.y;
            Ls[tq * 16 + 4 * u + 2][e] = x.z;
            Ls[tq * 16 + 4 * u + 3][e] = x.w;
        }
    }
    __syncthreads();
    const int t = tid >> 2, q = tid & 3;
    float v[16];
    float s = 0.f;
#pragma unroll
    for (int u = 0; u < 16; ++u) { v[u] = Ls[t][q * 16 + u]; s += v[u]; }
    s += __shfl_xor(s, 1, 4);
    s += __shfl_xor(s, 2, 4);
    const float inv = (s > 0.f) ? 1.0f / s : 0.f;
    float* dp = dispatch + (size_t)(t0 + t) * Em + q * 16;
    float* cb = combine  + (size_t)(t0 + t) * Em + q * 16;
#pragma unroll
    for (int u = 0; u < 4; ++u) {
        *reinterpret_cast<float4*>(dp + 4 * u) =
            make_float4(v[4 * u], v[4 * u + 1], v[4 * u + 2], v[4 * u + 3]);
        *reinterpret_cast<float4*>(cb + 4 * u) =
            make_float4(v[4 * u] * inv, v[4 * u + 1] * inv,
                        v[4 * u + 2] * inv, v[4 * u + 3] * inv);
    }
}

// ---------------------------------------------------------------------------
extern "C" void kernel_launch(void* const* d_in, const int* in_sizes, int n_in,
                              void* d_out, int out_size, void* d_ws, size_t ws_size,
                              hipStream_t stream) {
    const float* hid = (const float*)d_in[0];
    const float* W   = (const float*)d_in[1];
    float* out      = (float*)d_out;
    float* dispatch = out;
    float* combine  = out + (size_t)Tm * Em;
    float* probs    = out + 2 * (size_t)Tm * Em;

    const size_t wtB = sizeof(float) * (size_t)Hm * Em;   // 512 KB
    const size_t teB = sizeof(float) * (size_t)Tm * Em;   // 8 MB
    char* ws = (char*)d_ws;

    float* Wt = (float*)ws;
    size_t off = wtB;

    // pick largest split-K that fits: partials (nkq*teB) + probsT + dT
    int nkq = 1;
    if      (ws_size >= off + (8 + 2) * teB) nkq = 8;
    else if (ws_size >= off + (4 + 2) * teB) nkq = 4;
    else if (ws_size >= off + (2 + 2) * teB) nkq = 2;

    float* pl = (float*)(ws + off);
    off += (size_t)nkq * teB;
    float* probsT = (float*)(ws + off); off += teB;
    float* dT     = (float*)(ws + off); off += teB;

    k_wt<<<Hm / 64, 256, 0, stream>>>(W, Wt);
    k_router_partial<<<(Tm / BT) * nkq, 256, 0, stream>>>(hid, Wt, pl, nkq);
    k_reduce<<<Tm / 128, 128, 0, stream>>>(pl, nkq, probs, probsT);
    k_select<<<Em, 1024, 0, stream>>>(probsT, dT);
    k_finish<<<Tm / 64, 256, 0, stream>>>(dT, dispatch, combine);
}